// Round 5
// baseline (552.177 us; speedup 1.0000x reference)
//
#include <hip/hip_runtime.h>

#define Sn 1024
#define Dn 64
#define PH_LD 1032   // ushorts/row: 516 dw ≡ 4 (mod 32) -> conflict-min b64 write / b128 read / b64 read
#define K_LD 72
#define V_LD 72

typedef short v8s __attribute__((ext_vector_type(8)));
typedef unsigned short v8u __attribute__((ext_vector_type(8)));
typedef float v4f __attribute__((ext_vector_type(4)));

__device__ __forceinline__ unsigned short f2bf(float x) {
    union { float f; unsigned u; } v; v.f = x;
    return (unsigned short)((v.u + 0x7FFFu + ((v.u >> 16) & 1u)) >> 16);
}
__device__ __forceinline__ float bf2f(unsigned short h) {
    union { float f; unsigned u; } v; v.u = ((unsigned)h) << 16;
    return v.f;
}
__device__ __forceinline__ void split2(float x, unsigned short& h, unsigned short& l) {
    unsigned short hs = f2bf(x);
    h = hs; l = f2bf(x - bf2f(hs));
}

// ---------------- prep: K -> Khi/Klo bf16 (flat) ----------------
__global__ __launch_bounds__(256) void prep_k(const float* __restrict__ K,
    unsigned short* __restrict__ Khi, unsigned short* __restrict__ Klo)
{
    const size_t i = (((size_t)blockIdx.x << 8) + threadIdx.x) << 3;
    float x[8];
    *(float4*)&x[0] = *(const float4*)(K + i);
    *(float4*)&x[4] = *(const float4*)(K + i + 4);
    v8u h, l;
    #pragma unroll
    for (int j = 0; j < 8; ++j) {
        unsigned short hh, ll;
        split2(x[j], hh, ll);
        h[j] = hh; l[j] = ll;
    }
    *(v8u*)(Khi + i) = h;
    *(v8u*)(Klo + i) = l;
}

// ---------------- prep: V -> V^T bf16 [bh][d][k] ----------------
__global__ __launch_bounds__(256) void prep_v(const float* __restrict__ V,
    unsigned short* __restrict__ VT)
{
    __shared__ float Ts[64][65];
    const int bh = blockIdx.x >> 4, kt = blockIdx.x & 15;
    const int t = threadIdx.x;
    {
        const int r = t >> 2, cs = (t & 3) << 4;
        const float* src = V + ((size_t)bh * Sn + (kt << 6) + r) * Dn + cs;
        const float4 a = ((const float4*)src)[0];
        const float4 b = ((const float4*)src)[1];
        const float4 c = ((const float4*)src)[2];
        const float4 d = ((const float4*)src)[3];
        Ts[r][cs + 0] = a.x;  Ts[r][cs + 1] = a.y;  Ts[r][cs + 2] = a.z;  Ts[r][cs + 3] = a.w;
        Ts[r][cs + 4] = b.x;  Ts[r][cs + 5] = b.y;  Ts[r][cs + 6] = b.z;  Ts[r][cs + 7] = b.w;
        Ts[r][cs + 8] = c.x;  Ts[r][cs + 9] = c.y;  Ts[r][cs + 10] = c.z; Ts[r][cs + 11] = c.w;
        Ts[r][cs + 12] = d.x; Ts[r][cs + 13] = d.y; Ts[r][cs + 14] = d.z; Ts[r][cs + 15] = d.w;
    }
    __syncthreads();
    {
        const int dd = t >> 2, ks = (t & 3) << 4;
        unsigned short* dst = VT + ((size_t)bh << 16) + ((size_t)dd << 10) + (kt << 6) + ks;
        v8u o0, o1;
        #pragma unroll
        for (int j = 0; j < 8; ++j) o0[j] = f2bf(Ts[ks + j][dd]);
        #pragma unroll
        for (int j = 0; j < 8; ++j) o1[j] = f2bf(Ts[ks + 8 + j][dd]);
        *(v8u*)dst = o0;
        *(v8u*)(dst + 8) = o1;
    }
}

// ---------------- fused attention: global MFMA fragments, barrier-free loops ----
// Block: 16 q-rows, 4 waves, 4 blocks/CU (LDS = Ph only, 33 KB).
// Phase A: S^T = mfma(K,Q) hi/lo; K frags read directly from global (L2-resident).
// Phase B: ctx = (P V)*inv; V frags direct from global VT. 2 barriers total.
__global__ __launch_bounds__(256, 4) void fused_attn_g(
    const unsigned short* __restrict__ KhiG, const unsigned short* __restrict__ KloG,
    const unsigned short* __restrict__ VTG,  const float* __restrict__ Q,
    const int* __restrict__ M, float* __restrict__ attnO, float* __restrict__ ctxO)
{
    __shared__ unsigned short Ph[16][PH_LD];
    __shared__ float rsumW[4][16];
    __shared__ float invL[16];

    const int tid  = threadIdx.x;
    const int lane = tid & 63;
    const int w    = tid >> 6;
    const int fr   = lane & 15;
    const int g    = lane >> 4;

    // XCD swizzle: all 64 q-blocks of a bh land on one XCD (8192 % 8 == 0, bijective)
    const int swz = ((blockIdx.x & 7) << 10) + (blockIdx.x >> 3);
    const int bh = swz >> 6;
    const int q0 = (swz & 63) << 4;

    const float* Qb = Q + (size_t)bh * Sn * Dn + (size_t)q0 * Dn;
    const int*   Mb = M + (size_t)bh * Sn * Sn + (size_t)q0 * Sn;
    float*       Ab = attnO + (size_t)bh * Sn * Sn + (size_t)q0 * Sn;
    float*       Cb = ctxO  + (size_t)bh * Sn * Dn + (size_t)q0 * Dn;
    const unsigned short* KhiB = KhiG + ((size_t)bh << 16);
    const unsigned short* KloB = KloG + ((size_t)bh << 16);
    const unsigned short* VTB  = VTG  + ((size_t)bh << 16);

    // Q B-fragments: global float4 + in-reg split (once per block)
    v8s qh0, qh1, ql0, ql1;
    {
        const float* qp = Qb + fr * Dn + (g << 3);
        float x0[8], x1[8];
        *(float4*)&x0[0] = *(const float4*)qp;
        *(float4*)&x0[4] = *(const float4*)(qp + 4);
        *(float4*)&x1[0] = *(const float4*)(qp + 32);
        *(float4*)&x1[4] = *(const float4*)(qp + 36);
        #pragma unroll
        for (int i = 0; i < 8; ++i) {
            unsigned short hh, ll;
            split2(x0[i], hh, ll); qh0[i] = (short)hh; ql0[i] = (short)ll;
            split2(x1[i], hh, ll); qh1[i] = (short)hh; ql1[i] = (short)ll;
        }
    }

    // per-lane K fragment base: row = kt*64 + w*16 + fr, d-chunk = g*8 (+32)
    const unsigned short* khp = KhiB + ((size_t)((w << 4) + fr) << 6) + (g << 3);
    const unsigned short* klp = KloB + ((size_t)((w << 4) + fr) << 6) + (g << 3);
    const int* mp = Mb + (size_t)fr * Sn + (w << 4) + (g << 2);

    int4 mv = *(const int4*)mp;
    v8s kh0 = *(const v8s*)khp;
    v8s kh1 = *(const v8s*)(khp + 32);
    v8s kl0 = *(const v8s*)klp;
    v8s kl1 = *(const v8s*)(klp + 32);

    float rs = 0.f;

    // ---- Phase A: no barriers ----
    for (int kt = 0; kt < 16; ++kt) {
        v8s nh0 = kh0, nh1 = kh1, nl0 = kl0, nl1 = kl1;
        int4 mnext = mv;
        if (kt < 15) {
            const int off = (kt + 1) << 12;   // 64 rows * 64 d
            nh0 = *(const v8s*)(khp + off);
            nh1 = *(const v8s*)(khp + off + 32);
            nl0 = *(const v8s*)(klp + off);
            nl1 = *(const v8s*)(klp + off + 32);
            mnext = *(const int4*)(mp + ((kt + 1) << 6));
        }

        v4f acc = {0.f, 0.f, 0.f, 0.f};
        acc = __builtin_amdgcn_mfma_f32_16x16x32_bf16(kh0, qh0, acc, 0, 0, 0);
        acc = __builtin_amdgcn_mfma_f32_16x16x32_bf16(kh1, qh1, acc, 0, 0, 0);
        acc = __builtin_amdgcn_mfma_f32_16x16x32_bf16(kl0, qh0, acc, 0, 0, 0);
        acc = __builtin_amdgcn_mfma_f32_16x16x32_bf16(kl1, qh1, acc, 0, 0, 0);
        acc = __builtin_amdgcn_mfma_f32_16x16x32_bf16(kh0, ql0, acc, 0, 0, 0);
        acc = __builtin_amdgcn_mfma_f32_16x16x32_bf16(kh1, ql1, acc, 0, 0, 0);

        const float e0 = mv.x ? 1.0f : __expf(acc[0]);
        const float e1 = mv.y ? 1.0f : __expf(acc[1]);
        const float e2 = mv.z ? 1.0f : __expf(acc[2]);
        const float e3 = mv.w ? 1.0f : __expf(acc[3]);
        rs += (e0 + e1) + (e2 + e3);
        ushort4 pk;
        pk.x = f2bf(e0); pk.y = f2bf(e1); pk.z = f2bf(e2); pk.w = f2bf(e3);
        *(ushort4*)&Ph[fr][(kt << 6) + (w << 4) + (g << 2)] = pk;

        kh0 = nh0; kh1 = nh1; kl0 = nl0; kl1 = nl1;
        mv = mnext;
    }

    // per-lane V fragment base: d-row = w*16 + fr, k-chunk = g*8
    const unsigned short* vp = VTB + ((size_t)((w << 4) + fr) << 10) + (g << 3);
    v8s vb0 = *(const v8s*)vp;          // kt=0, k 0..31 slice
    v8s vb1 = *(const v8s*)(vp + 32);   // kt=0, k 32..63 slice

    // ---- row-sum reduce (2 barriers, only sync points in kernel) ----
    rs += __shfl_xor(rs, 16);
    rs += __shfl_xor(rs, 32);
    if (g == 0) rsumW[w][fr] = rs;
    __syncthreads();                    // Ph writes + rsumW visible
    if (tid < 16) {
        const float s = rsumW[0][tid] + rsumW[1][tid] + rsumW[2][tid] + rsumW[3][tid];
        invL[tid] = 1.0f / s;
    }
    __syncthreads();                    // invL visible

    // ---- Phase B: ctx = (P V) * inv, no barriers ----
    const int dcol = (w << 4) + fr;
    v4f accp = {0.f, 0.f, 0.f, 0.f};
    for (int kt = 0; kt < 16; ++kt) {
        v8s vn0 = vb0, vn1 = vb1;
        if (kt < 15) {
            const int off = (kt + 1) << 6;
            vn0 = *(const v8s*)(vp + off);
            vn1 = *(const v8s*)(vp + off + 32);
        }
        const v8s a0 = *(const v8s*)&Ph[fr][(kt << 6) + (g << 3)];
        const v8s a1 = *(const v8s*)&Ph[fr][(kt << 6) + 32 + (g << 3)];
        accp = __builtin_amdgcn_mfma_f32_16x16x32_bf16(a0, vb0, accp, 0, 0, 0);
        accp = __builtin_amdgcn_mfma_f32_16x16x32_bf16(a1, vb1, accp, 0, 0, 0);
        vb0 = vn0; vb1 = vn1;
    }
    #pragma unroll
    for (int r = 0; r < 4; ++r) {
        const int q = (g << 2) + r;
        Cb[(size_t)q * Dn + dcol] = accp[r] * invL[q];
    }

    // ---- write normalized attn ----
    {
        const int qq = tid >> 4, ii = tid & 15;
        const float inv = invL[qq];
        float* arow = Ab + (size_t)qq * Sn;
        #pragma unroll
        for (int c = 0; c < 16; ++c) {
            const int k0 = (c << 6) + (ii << 2);
            const ushort4 p = *(const ushort4*)&Ph[qq][k0];
            float4 o;
            o.x = bf2f(p.x) * inv; o.y = bf2f(p.y) * inv;
            o.z = bf2f(p.z) * inv; o.w = bf2f(p.w) * inv;
            *(float4*)(arow + k0) = o;
        }
    }
}

// ---------------- fallback (round-3 kernel, in-kernel split) ----------------
__global__ __launch_bounds__(256, 3) void fused_attn_fb(
    const float* __restrict__ Q, const float* __restrict__ K,
    const float* __restrict__ V, const int* __restrict__ M,
    float* __restrict__ attnO, float* __restrict__ ctxO)
{
    __shared__ unsigned short Ph[16][1048];
    __shared__ __align__(16) unsigned short Kraw[2 * 64 * K_LD];
    __shared__ float rsumW[4][16];
    __shared__ float invL[16];

    unsigned short (*Khi)[K_LD] = (unsigned short (*)[K_LD])Kraw;
    unsigned short (*Klo)[K_LD] = (unsigned short (*)[K_LD])(Kraw + 64 * K_LD);
    unsigned short (*Vt)[V_LD]  = (unsigned short (*)[V_LD])Kraw;

    const int tid  = threadIdx.x;
    const int lane = tid & 63;
    const int w    = tid >> 6;
    const int fr   = lane & 15;
    const int g    = lane >> 4;

    const int bh = blockIdx.x >> 6;
    const int q0 = (blockIdx.x & 63) << 4;

    const float* Qb = Q + (size_t)bh * Sn * Dn + (size_t)q0 * Dn;
    const float* Kb = K + (size_t)bh * Sn * Dn;
    const float* Vb = V + (size_t)bh * Sn * Dn;
    const int*   Mb = M + (size_t)bh * Sn * Sn + (size_t)q0 * Sn;
    float*       Ab = attnO + (size_t)bh * Sn * Sn + (size_t)q0 * Sn;
    float*       Cb = ctxO  + (size_t)bh * Sn * Dn + (size_t)q0 * Dn;

    v8s qh0, qh1, ql0, ql1;
    {
        const float* qp = Qb + fr * Dn + (g << 3);
        float x0[8], x1[8];
        *(float4*)&x0[0] = *(const float4*)qp;
        *(float4*)&x0[4] = *(const float4*)(qp + 4);
        *(float4*)&x1[0] = *(const float4*)(qp + 32);
        *(float4*)&x1[4] = *(const float4*)(qp + 36);
        #pragma unroll
        for (int i = 0; i < 8; ++i) {
            unsigned short hh, ll;
            split2(x0[i], hh, ll); qh0[i] = (short)hh; ql0[i] = (short)ll;
            split2(x1[i], hh, ll); qh1[i] = (short)hh; ql1[i] = (short)ll;
        }
    }

    const int srow = tid >> 4;
    const int sc4  = (tid & 15) << 2;

    const int* mp = Mb + (size_t)fr * Sn + (w << 4) + (g << 2);
    int4 mv = *(const int4*)mp;

    float4 ka[4];
    #pragma unroll
    for (int i = 0; i < 4; ++i)
        ka[i] = *(const float4*)(Kb + (size_t)(srow + (i << 4)) * Dn + sc4);

    float rs = 0.f;

    for (int kt = 0; kt < 16; ++kt) {
        __syncthreads();
        float4 kb[4];
        if (kt < 15) {
            const float* kn = Kb + (size_t)((kt + 1) << 6) * Dn;
            #pragma unroll
            for (int i = 0; i < 4; ++i)
                kb[i] = *(const float4*)(kn + (size_t)(srow + (i << 4)) * Dn + sc4);
        }
        int4 mnext = mv;
        if (kt < 15) mnext = *(const int4*)(mp + ((kt + 1) << 6));

        #pragma unroll
        for (int i = 0; i < 4; ++i) {
            const int row = srow + (i << 4);
            ushort4 hv, lv;
            split2(ka[i].x, hv.x, lv.x); split2(ka[i].y, hv.y, lv.y);
            split2(ka[i].z, hv.z, lv.z); split2(ka[i].w, hv.w, lv.w);
            *(ushort4*)&Khi[row][sc4] = hv;
            *(ushort4*)&Klo[row][sc4] = lv;
        }
        __syncthreads();

        const int krow = (w << 4) + fr;
        const v8s kh0 = *(const v8s*)&Khi[krow][(g << 3)];
        const v8s kh1 = *(const v8s*)&Khi[krow][32 + (g << 3)];
        const v8s kl0 = *(const v8s*)&Klo[krow][(g << 3)];
        const v8s kl1 = *(const v8s*)&Klo[krow][32 + (g << 3)];

        v4f acc = {0.f, 0.f, 0.f, 0.f};
        acc = __builtin_amdgcn_mfma_f32_16x16x32_bf16(kh0, qh0, acc, 0, 0, 0);
        acc = __builtin_amdgcn_mfma_f32_16x16x32_bf16(kh1, qh1, acc, 0, 0, 0);
        acc = __builtin_amdgcn_mfma_f32_16x16x32_bf16(kl0, qh0, acc, 0, 0, 0);
        acc = __builtin_amdgcn_mfma_f32_16x16x32_bf16(kl1, qh1, acc, 0, 0, 0);
        acc = __builtin_amdgcn_mfma_f32_16x16x32_bf16(kh0, ql0, acc, 0, 0, 0);
        acc = __builtin_amdgcn_mfma_f32_16x16x32_bf16(kh1, ql1, acc, 0, 0, 0);

        const float e0 = mv.x ? 1.0f : __expf(acc[0]);
        const float e1 = mv.y ? 1.0f : __expf(acc[1]);
        const float e2 = mv.z ? 1.0f : __expf(acc[2]);
        const float e3 = mv.w ? 1.0f : __expf(acc[3]);
        rs += (e0 + e1) + (e2 + e3);
        ushort4 pk;
        pk.x = f2bf(e0); pk.y = f2bf(e1); pk.z = f2bf(e2); pk.w = f2bf(e3);
        *(ushort4*)&Ph[fr][(kt << 6) + (w << 4) + (g << 2)] = pk;

        mv = mnext;
        #pragma unroll
        for (int i = 0; i < 4; ++i) ka[i] = kb[i];
    }

    rs += __shfl_xor(rs, 16);
    rs += __shfl_xor(rs, 32);
    if (g == 0) rsumW[w][fr] = rs;
    __syncthreads();
    if (tid < 16) {
        const float s = rsumW[0][tid] + rsumW[1][tid] + rsumW[2][tid] + rsumW[3][tid];
        invL[tid] = 1.0f / s;
    }
    __syncthreads();

    const int dcol = (w << 4) + fr;
    float4 va[4];
    #pragma unroll
    for (int i = 0; i < 4; ++i)
        va[i] = *(const float4*)(Vb + (size_t)(srow + (i << 4)) * Dn + sc4);

    v4f accp = {0.f, 0.f, 0.f, 0.f};
    for (int kt = 0; kt < 16; ++kt) {
        __syncthreads();
        float4 vb[4];
        if (kt < 15) {
            const float* vn = Vb + (size_t)((kt + 1) << 6) * Dn;
            #pragma unroll
            for (int i = 0; i < 4; ++i)
                vb[i] = *(const float4*)(vn + (size_t)(srow + (i << 4)) * Dn + sc4);
        }
        #pragma unroll
        for (int i = 0; i < 4; ++i) {
            const int row = srow + (i << 4);
            Vt[sc4 + 0][row] = f2bf(va[i].x);
            Vt[sc4 + 1][row] = f2bf(va[i].y);
            Vt[sc4 + 2][row] = f2bf(va[i].z);
            Vt[sc4 + 3][row] = f2bf(va[i].w);
        }
        __syncthreads();

        #pragma unroll
        for (int c = 0; c < 2; ++c) {
            const int kc = (kt << 6) + (c << 5);
            const v8s a = *(const v8s*)&Ph[fr][kc + (g << 3)];
            const v8s b = *(const v8s*)&Vt[dcol][(c << 5) + (g << 3)];
            accp = __builtin_amdgcn_mfma_f32_16x16x32_bf16(a, b, accp, 0, 0, 0);
        }
        #pragma unroll
        for (int i = 0; i < 4; ++i) va[i] = vb[i];
    }
    #pragma unroll
    for (int r = 0; r < 4; ++r) {
        const int q = (g << 2) + r;
        Cb[(size_t)q * Dn + dcol] = accp[r] * invL[q];
    }

    {
        const int qq = tid >> 4, ii = tid & 15;
        const float inv = invL[qq];
        float* arow = Ab + (size_t)qq * Sn;
        #pragma unroll
        for (int c = 0; c < 16; ++c) {
            const int k0 = (c << 6) + (ii << 2);
            const ushort4 p = *(const ushort4*)&Ph[qq][k0];
            float4 o;
            o.x = bf2f(p.x) * inv; o.y = bf2f(p.y) * inv;
            o.z = bf2f(p.z) * inv; o.w = bf2f(p.w) * inv;
            *(float4*)(arow + k0) = o;
        }
    }
}

extern "C" void kernel_launch(void* const* d_in, const int* in_sizes, int n_in,
                              void* d_out, int out_size, void* d_ws, size_t ws_size,
                              hipStream_t stream) {
    const float* Q    = (const float*)d_in[0];
    const float* K    = (const float*)d_in[1];
    const float* V    = (const float*)d_in[2];
    const int*   mask = (const int*)d_in[3];

    float* ctx  = (float*)d_out;                           // (B,H,S,D)
    float* attn = (float*)d_out + (size_t)128 * Sn * Dn;   // (B,H,S,S)

    const size_t NELEM = (size_t)128 * Sn * Dn;            // 8,388,608
    const size_t NEED  = NELEM * 2 * 3;                    // Khi + Klo + VT (bf16)

    if (ws_size >= NEED) {
        unsigned short* Khi = (unsigned short*)d_ws;
        unsigned short* Klo = Khi + NELEM;
        unsigned short* VT  = Klo + NELEM;
        prep_k<<<4096, 256, 0, stream>>>(K, Khi, Klo);
        prep_v<<<2048, 256, 0, stream>>>(V, VT);
        fused_attn_g<<<128 * 64, 256, 0, stream>>>(Khi, Klo, VT, Q, mask, attn, ctx);
    } else {
        fused_attn_fb<<<128 * 64, 256, 0, stream>>>(Q, K, V, mask, attn, ctx);
    }
}

// Round 6
// 450.003 us; speedup vs baseline: 1.2271x; 1.2271x over previous
//
#include <hip/hip_runtime.h>

#define Sn 1024
#define Dn 64
#define PH_LD 1032   // ushorts/row: 516 dw ≡ 4 (mod 32) -> conflict-min b64 write / b128 read / b64 read
#define K_LD 72
#define V_LD 72

typedef short v8s __attribute__((ext_vector_type(8)));
typedef unsigned short v8u __attribute__((ext_vector_type(8)));
typedef float v4f __attribute__((ext_vector_type(4)));

__device__ __forceinline__ unsigned short f2bf(float x) {
    union { float f; unsigned u; } v; v.f = x;
    return (unsigned short)((v.u + 0x7FFFu + ((v.u >> 16) & 1u)) >> 16);
}
__device__ __forceinline__ float bf2f(unsigned short h) {
    union { float f; unsigned u; } v; v.u = ((unsigned)h) << 16;
    return v.f;
}
__device__ __forceinline__ void split2(float x, unsigned short& h, unsigned short& l) {
    unsigned short hs = f2bf(x);
    h = hs; l = f2bf(x - bf2f(hs));
}

// ---------------- prep: K -> Khi/Klo bf16 (flat) ----------------
__global__ __launch_bounds__(256) void prep_k(const float* __restrict__ K,
    unsigned short* __restrict__ Khi, unsigned short* __restrict__ Klo)
{
    const size_t i = (((size_t)blockIdx.x << 8) + threadIdx.x) << 3;
    float x[8];
    *(float4*)&x[0] = *(const float4*)(K + i);
    *(float4*)&x[4] = *(const float4*)(K + i + 4);
    v8u h, l;
    #pragma unroll
    for (int j = 0; j < 8; ++j) {
        unsigned short hh, ll;
        split2(x[j], hh, ll);
        h[j] = hh; l[j] = ll;
    }
    *(v8u*)(Khi + i) = h;
    *(v8u*)(Klo + i) = l;
}

// ---------------- prep: V -> V^T bf16 [bh][d][k] ----------------
__global__ __launch_bounds__(256) void prep_v(const float* __restrict__ V,
    unsigned short* __restrict__ VT)
{
    __shared__ float Ts[64][65];
    const int bh = blockIdx.x >> 4, kt = blockIdx.x & 15;
    const int t = threadIdx.x;
    {
        const int r = t >> 2, cs = (t & 3) << 4;
        const float* src = V + ((size_t)bh * Sn + (kt << 6) + r) * Dn + cs;
        const float4 a = ((const float4*)src)[0];
        const float4 b = ((const float4*)src)[1];
        const float4 c = ((const float4*)src)[2];
        const float4 d = ((const float4*)src)[3];
        Ts[r][cs + 0] = a.x;  Ts[r][cs + 1] = a.y;  Ts[r][cs + 2] = a.z;  Ts[r][cs + 3] = a.w;
        Ts[r][cs + 4] = b.x;  Ts[r][cs + 5] = b.y;  Ts[r][cs + 6] = b.z;  Ts[r][cs + 7] = b.w;
        Ts[r][cs + 8] = c.x;  Ts[r][cs + 9] = c.y;  Ts[r][cs + 10] = c.z; Ts[r][cs + 11] = c.w;
        Ts[r][cs + 12] = d.x; Ts[r][cs + 13] = d.y; Ts[r][cs + 14] = d.z; Ts[r][cs + 15] = d.w;
    }
    __syncthreads();
    {
        const int dd = t >> 2, ks = (t & 3) << 4;
        unsigned short* dst = VT + ((size_t)bh << 16) + ((size_t)dd << 10) + (kt << 6) + ks;
        v8u o0, o1;
        #pragma unroll
        for (int j = 0; j < 8; ++j) o0[j] = f2bf(Ts[ks + j][dd]);
        #pragma unroll
        for (int j = 0; j < 8; ++j) o1[j] = f2bf(Ts[ks + 8 + j][dd]);
        *(v8u*)dst = o0;
        *(v8u*)(dst + 8) = o1;
    }
}

// ---------------- prep: mask int32 -> bit-packed u64 words ----------------
// word w, bit j  <=>  mask[w*64 + j] != 0. Pure streaming pass.
__global__ __launch_bounds__(256) void prep_m(const int* __restrict__ M,
    unsigned long long* __restrict__ MW)
{
    const int NW = 2097152;   // 128*1024*1024 / 64
    const int lane = threadIdx.x & 63;
    const int wave = (blockIdx.x << 2) + (threadIdx.x >> 6);
    const int nwaves = gridDim.x << 2;
    for (int w0 = wave << 3; w0 < NW; w0 += nwaves << 3) {
        unsigned long long b[8];
        #pragma unroll
        for (int s = 0; s < 8; ++s) {
            const int v = M[((size_t)(w0 + s) << 6) + lane];
            b[s] = __ballot(v != 0);
        }
        if (lane == 0) {
            ulonglong2* dst = (ulonglong2*)(MW + w0);
            ulonglong2 p0, p1, p2, p3;
            p0.x = b[0]; p0.y = b[1]; p1.x = b[2]; p1.y = b[3];
            p2.x = b[4]; p2.y = b[5]; p3.x = b[6]; p3.y = b[7];
            dst[0] = p0; dst[1] = p1; dst[2] = p2; dst[3] = p3;
        }
    }
}

// ---------------- fused attention (bit-mask, LDS-staged, NT stores) ----------
// Block: 16 q-rows, 4 waves, 3 blocks/CU. All loop loads L2-resident;
// only HBM stream is the attn/ctx stores (non-temporal).
__global__ __launch_bounds__(256, 3) void fused_attn_b(
    const unsigned short* __restrict__ KhiG, const unsigned short* __restrict__ KloG,
    const unsigned short* __restrict__ VTG,  const float* __restrict__ Q,
    const unsigned long long* __restrict__ MW,
    float* __restrict__ attnO, float* __restrict__ ctxO)
{
    __shared__ unsigned short Ph[16][PH_LD];
    __shared__ __align__(16) unsigned short Kraw[2 * 64 * K_LD];
    __shared__ float rsumW[4][16];
    __shared__ float invL[16];

    unsigned short (*Khi)[K_LD] = (unsigned short (*)[K_LD])Kraw;
    unsigned short (*Klo)[K_LD] = (unsigned short (*)[K_LD])(Kraw + 64 * K_LD);
    unsigned short (*Vt)[V_LD]  = (unsigned short (*)[V_LD])Kraw;

    const int tid  = threadIdx.x;
    const int lane = tid & 63;
    const int w    = tid >> 6;
    const int fr   = lane & 15;
    const int g    = lane >> 4;

    // bijective XCD swizzle: all 64 q-blocks of one bh land on one XCD
    const int swz = ((blockIdx.x & 7) << 10) + (blockIdx.x >> 3);
    const int bh = swz >> 6;
    const int q0 = (swz & 63) << 4;

    const float* Qb = Q + (size_t)bh * Sn * Dn + (size_t)q0 * Dn;
    float*       Ab = attnO + (size_t)bh * Sn * Sn + (size_t)q0 * Sn;
    float*       Cb = ctxO  + (size_t)bh * Sn * Dn + (size_t)q0 * Dn;
    const unsigned short* KhiB = KhiG + ((size_t)bh << 16);
    const unsigned short* KloB = KloG + ((size_t)bh << 16);
    const unsigned short* VTB  = VTG  + ((size_t)bh << 16);
    const unsigned long long* mwp = MW + ((size_t)bh << 14) + ((size_t)(q0 + fr) << 4);

    // Q B-fragments: global float4 + in-reg split (once per block)
    v8s qh0, qh1, ql0, ql1;
    {
        const float* qp = Qb + fr * Dn + (g << 3);
        float x0[8], x1[8];
        *(float4*)&x0[0] = *(const float4*)qp;
        *(float4*)&x0[4] = *(const float4*)(qp + 4);
        *(float4*)&x1[0] = *(const float4*)(qp + 32);
        *(float4*)&x1[4] = *(const float4*)(qp + 36);
        #pragma unroll
        for (int i = 0; i < 8; ++i) {
            unsigned short hh, ll;
            split2(x0[i], hh, ll); qh0[i] = (short)hh; ql0[i] = (short)ll;
            split2(x1[i], hh, ll); qh1[i] = (short)hh; ql1[i] = (short)ll;
        }
    }

    const int srow = tid >> 2;          // 0..63
    const int sseg = (tid & 3) << 4;    // ushort col: 0/16/32/48
    const int sh   = (w << 4) + (g << 2);

    unsigned long long mw = mwp[0];

    // preload K tile 0 (bf16 hi/lo) into regs
    uint4 ch0, ch1, cl0, cl1;
    {
        const uint4* ph = (const uint4*)(KhiB + (size_t)srow * Dn + sseg);
        const uint4* pl = (const uint4*)(KloB + (size_t)srow * Dn + sseg);
        ch0 = ph[0]; ch1 = ph[1]; cl0 = pl[0]; cl1 = pl[1];
    }

    float rs = 0.f;

    // ---- Phase A ----
    for (int kt = 0; kt < 16; ++kt) {
        __syncthreads();   // prev tile's frag reads complete
        *(uint4*)&Khi[srow][sseg]     = ch0;
        *(uint4*)&Khi[srow][sseg + 8] = ch1;
        *(uint4*)&Klo[srow][sseg]     = cl0;
        *(uint4*)&Klo[srow][sseg + 8] = cl1;

        unsigned long long mnext = mw;
        if (kt < 15) {
            const uint4* ph = (const uint4*)(KhiB + (size_t)((kt + 1) * 64 + srow) * Dn + sseg);
            const uint4* pl = (const uint4*)(KloB + (size_t)((kt + 1) * 64 + srow) * Dn + sseg);
            ch0 = ph[0]; ch1 = ph[1]; cl0 = pl[0]; cl1 = pl[1];
            mnext = mwp[kt + 1];
        }
        __syncthreads();

        const int krow = (w << 4) + fr;
        const v8s kh0 = *(const v8s*)&Khi[krow][(g << 3)];
        const v8s kh1 = *(const v8s*)&Khi[krow][32 + (g << 3)];
        const v8s kl0 = *(const v8s*)&Klo[krow][(g << 3)];
        const v8s kl1 = *(const v8s*)&Klo[krow][32 + (g << 3)];

        v4f acc = {0.f, 0.f, 0.f, 0.f};
        acc = __builtin_amdgcn_mfma_f32_16x16x32_bf16(kh0, qh0, acc, 0, 0, 0);
        acc = __builtin_amdgcn_mfma_f32_16x16x32_bf16(kh1, qh1, acc, 0, 0, 0);
        acc = __builtin_amdgcn_mfma_f32_16x16x32_bf16(kl0, qh0, acc, 0, 0, 0);
        acc = __builtin_amdgcn_mfma_f32_16x16x32_bf16(kl1, qh1, acc, 0, 0, 0);
        acc = __builtin_amdgcn_mfma_f32_16x16x32_bf16(kh0, ql0, acc, 0, 0, 0);
        acc = __builtin_amdgcn_mfma_f32_16x16x32_bf16(kh1, ql1, acc, 0, 0, 0);

        const unsigned mb = (unsigned)(mw >> sh);
        const float e0 = (mb & 1u) ? 1.0f : __expf(acc[0]);
        const float e1 = (mb & 2u) ? 1.0f : __expf(acc[1]);
        const float e2 = (mb & 4u) ? 1.0f : __expf(acc[2]);
        const float e3 = (mb & 8u) ? 1.0f : __expf(acc[3]);
        rs += (e0 + e1) + (e2 + e3);
        ushort4 pk;
        pk.x = f2bf(e0); pk.y = f2bf(e1); pk.z = f2bf(e2); pk.w = f2bf(e3);
        *(ushort4*)&Ph[fr][(kt << 6) + (w << 4) + (g << 2)] = pk;

        mw = mnext;
    }

    // preload V tile 0 early (hides latency under the reduction)
    uint4 cv0, cv1;
    {
        const uint4* pv = (const uint4*)(VTB + ((size_t)srow << 10) + sseg);
        cv0 = pv[0]; cv1 = pv[1];
    }

    // ---- row-sum reduce ----
    rs += __shfl_xor(rs, 16);
    rs += __shfl_xor(rs, 32);
    if (g == 0) rsumW[w][fr] = rs;
    __syncthreads();
    if (tid < 16) {
        const float s = rsumW[0][tid] + rsumW[1][tid] + rsumW[2][tid] + rsumW[3][tid];
        invL[tid] = 1.0f / s;
    }

    // ---- Phase B: ctx = (P V) * inv ----
    const int dcol = (w << 4) + fr;
    v4f accp = {0.f, 0.f, 0.f, 0.f};
    for (int kt = 0; kt < 16; ++kt) {
        __syncthreads();   // prev Vt reads done (and invL ready on first iter)
        *(uint4*)&Vt[srow][sseg]     = cv0;
        *(uint4*)&Vt[srow][sseg + 8] = cv1;
        if (kt < 15) {
            const uint4* pv = (const uint4*)(VTB + ((size_t)srow << 10) + ((kt + 1) << 6) + sseg);
            cv0 = pv[0]; cv1 = pv[1];
        }
        __syncthreads();

        #pragma unroll
        for (int c = 0; c < 2; ++c) {
            const v8s a = *(const v8s*)&Ph[fr][(kt << 6) + (c << 5) + (g << 3)];
            const v8s b = *(const v8s*)&Vt[dcol][(c << 5) + (g << 3)];
            accp = __builtin_amdgcn_mfma_f32_16x16x32_bf16(a, b, accp, 0, 0, 0);
        }
    }
    #pragma unroll
    for (int r = 0; r < 4; ++r) {
        const int q = (g << 2) + r;
        __builtin_nontemporal_store(accp[r] * invL[q], &Cb[(size_t)q * Dn + dcol]);
    }

    // ---- write normalized attn (non-temporal) ----
    {
        const int qq = tid >> 4, ii = tid & 15;
        const float inv = invL[qq];
        float* arow = Ab + (size_t)qq * Sn;
        #pragma unroll
        for (int c = 0; c < 16; ++c) {
            const int k0 = (c << 6) + (ii << 2);
            const ushort4 p = *(const ushort4*)&Ph[qq][k0];
            v4f o;
            o[0] = bf2f(p.x) * inv; o[1] = bf2f(p.y) * inv;
            o[2] = bf2f(p.z) * inv; o[3] = bf2f(p.w) * inv;
            __builtin_nontemporal_store(o, (v4f*)(arow + k0));
        }
    }
}

// ---------------- fallback (round-3 kernel, in-kernel split) ----------------
__global__ __launch_bounds__(256, 3) void fused_attn_fb(
    const float* __restrict__ Q, const float* __restrict__ K,
    const float* __restrict__ V, const int* __restrict__ M,
    float* __restrict__ attnO, float* __restrict__ ctxO)
{
    __shared__ unsigned short Ph[16][1048];
    __shared__ __align__(16) unsigned short Kraw[2 * 64 * K_LD];
    __shared__ float rsumW[4][16];
    __shared__ float invL[16];

    unsigned short (*Khi)[K_LD] = (unsigned short (*)[K_LD])Kraw;
    unsigned short (*Klo)[K_LD] = (unsigned short (*)[K_LD])(Kraw + 64 * K_LD);
    unsigned short (*Vt)[V_LD]  = (unsigned short (*)[V_LD])Kraw;

    const int tid  = threadIdx.x;
    const int lane = tid & 63;
    const int w    = tid >> 6;
    const int fr   = lane & 15;
    const int g    = lane >> 4;

    const int bh = blockIdx.x >> 6;
    const int q0 = (blockIdx.x & 63) << 4;

    const float* Qb = Q + (size_t)bh * Sn * Dn + (size_t)q0 * Dn;
    const float* Kb = K + (size_t)bh * Sn * Dn;
    const float* Vb = V + (size_t)bh * Sn * Dn;
    const int*   Mb = M + (size_t)bh * Sn * Sn + (size_t)q0 * Sn;
    float*       Ab = attnO + (size_t)bh * Sn * Sn + (size_t)q0 * Sn;
    float*       Cb = ctxO  + (size_t)bh * Sn * Dn + (size_t)q0 * Dn;

    v8s qh0, qh1, ql0, ql1;
    {
        const float* qp = Qb + fr * Dn + (g << 3);
        float x0[8], x1[8];
        *(float4*)&x0[0] = *(const float4*)qp;
        *(float4*)&x0[4] = *(const float4*)(qp + 4);
        *(float4*)&x1[0] = *(const float4*)(qp + 32);
        *(float4*)&x1[4] = *(const float4*)(qp + 36);
        #pragma unroll
        for (int i = 0; i < 8; ++i) {
            unsigned short hh, ll;
            split2(x0[i], hh, ll); qh0[i] = (short)hh; ql0[i] = (short)ll;
            split2(x1[i], hh, ll); qh1[i] = (short)hh; ql1[i] = (short)ll;
        }
    }

    const int srow = tid >> 4;
    const int sc4  = (tid & 15) << 2;

    const int* mp = Mb + (size_t)fr * Sn + (w << 4) + (g << 2);
    int4 mv = *(const int4*)mp;

    float4 ka[4];
    #pragma unroll
    for (int i = 0; i < 4; ++i)
        ka[i] = *(const float4*)(Kb + (size_t)(srow + (i << 4)) * Dn + sc4);

    float rs = 0.f;

    for (int kt = 0; kt < 16; ++kt) {
        __syncthreads();
        float4 kb[4];
        if (kt < 15) {
            const float* kn = Kb + (size_t)((kt + 1) << 6) * Dn;
            #pragma unroll
            for (int i = 0; i < 4; ++i)
                kb[i] = *(const float4*)(kn + (size_t)(srow + (i << 4)) * Dn + sc4);
        }
        int4 mnext = mv;
        if (kt < 15) mnext = *(const int4*)(mp + ((kt + 1) << 6));

        #pragma unroll
        for (int i = 0; i < 4; ++i) {
            const int row = srow + (i << 4);
            ushort4 hv, lv;
            split2(ka[i].x, hv.x, lv.x); split2(ka[i].y, hv.y, lv.y);
            split2(ka[i].z, hv.z, lv.z); split2(ka[i].w, hv.w, lv.w);
            *(ushort4*)&Khi[row][sc4] = hv;
            *(ushort4*)&Klo[row][sc4] = lv;
        }
        __syncthreads();

        const int krow = (w << 4) + fr;
        const v8s kh0 = *(const v8s*)&Khi[krow][(g << 3)];
        const v8s kh1 = *(const v8s*)&Khi[krow][32 + (g << 3)];
        const v8s kl0 = *(const v8s*)&Klo[krow][(g << 3)];
        const v8s kl1 = *(const v8s*)&Klo[krow][32 + (g << 3)];

        v4f acc = {0.f, 0.f, 0.f, 0.f};
        acc = __builtin_amdgcn_mfma_f32_16x16x32_bf16(kh0, qh0, acc, 0, 0, 0);
        acc = __builtin_amdgcn_mfma_f32_16x16x32_bf16(kh1, qh1, acc, 0, 0, 0);
        acc = __builtin_amdgcn_mfma_f32_16x16x32_bf16(kl0, qh0, acc, 0, 0, 0);
        acc = __builtin_amdgcn_mfma_f32_16x16x32_bf16(kl1, qh1, acc, 0, 0, 0);
        acc = __builtin_amdgcn_mfma_f32_16x16x32_bf16(kh0, ql0, acc, 0, 0, 0);
        acc = __builtin_amdgcn_mfma_f32_16x16x32_bf16(kh1, ql1, acc, 0, 0, 0);

        const float e0 = mv.x ? 1.0f : __expf(acc[0]);
        const float e1 = mv.y ? 1.0f : __expf(acc[1]);
        const float e2 = mv.z ? 1.0f : __expf(acc[2]);
        const float e3 = mv.w ? 1.0f : __expf(acc[3]);
        rs += (e0 + e1) + (e2 + e3);
        ushort4 pk;
        pk.x = f2bf(e0); pk.y = f2bf(e1); pk.z = f2bf(e2); pk.w = f2bf(e3);
        *(ushort4*)&Ph[fr][(kt << 6) + (w << 4) + (g << 2)] = pk;

        mv = mnext;
        #pragma unroll
        for (int i = 0; i < 4; ++i) ka[i] = kb[i];
    }

    rs += __shfl_xor(rs, 16);
    rs += __shfl_xor(rs, 32);
    if (g == 0) rsumW[w][fr] = rs;
    __syncthreads();
    if (tid < 16) {
        const float s = rsumW[0][tid] + rsumW[1][tid] + rsumW[2][tid] + rsumW[3][tid];
        invL[tid] = 1.0f / s;
    }
    __syncthreads();

    const int dcol = (w << 4) + fr;
    float4 va[4];
    #pragma unroll
    for (int i = 0; i < 4; ++i)
        va[i] = *(const float4*)(Vb + (size_t)(srow + (i << 4)) * Dn + sc4);

    v4f accp = {0.f, 0.f, 0.f, 0.f};
    for (int kt = 0; kt < 16; ++kt) {
        __syncthreads();
        float4 vb[4];
        if (kt < 15) {
            const float* vn = Vb + (size_t)((kt + 1) << 6) * Dn;
            #pragma unroll
            for (int i = 0; i < 4; ++i)
                vb[i] = *(const float4*)(vn + (size_t)(srow + (i << 4)) * Dn + sc4);
        }
        #pragma unroll
        for (int i = 0; i < 4; ++i) {
            const int row = srow + (i << 4);
            Vt[sc4 + 0][row] = f2bf(va[i].x);
            Vt[sc4 + 1][row] = f2bf(va[i].y);
            Vt[sc4 + 2][row] = f2bf(va[i].z);
            Vt[sc4 + 3][row] = f2bf(va[i].w);
        }
        __syncthreads();

        #pragma unroll
        for (int c = 0; c < 2; ++c) {
            const int kc = (kt << 6) + (c << 5);
            const v8s a = *(const v8s*)&Ph[fr][kc + (g << 3)];
            const v8s b = *(const v8s*)&Vt[dcol][(c << 5) + (g << 3)];
            accp = __builtin_amdgcn_mfma_f32_16x16x32_bf16(a, b, accp, 0, 0, 0);
        }
        #pragma unroll
        for (int i = 0; i < 4; ++i) va[i] = vb[i];
    }
    #pragma unroll
    for (int r = 0; r < 4; ++r) {
        const int q = (g << 2) + r;
        Cb[(size_t)q * Dn + dcol] = accp[r] * invL[q];
    }

    {
        const int qq = tid >> 4, ii = tid & 15;
        const float inv = invL[qq];
        float* arow = Ab + (size_t)qq * Sn;
        #pragma unroll
        for (int c = 0; c < 16; ++c) {
            const int k0 = (c << 6) + (ii << 2);
            const ushort4 p = *(const ushort4*)&Ph[qq][k0];
            float4 o;
            o.x = bf2f(p.x) * inv; o.y = bf2f(p.y) * inv;
            o.z = bf2f(p.z) * inv; o.w = bf2f(p.w) * inv;
            *(float4*)(arow + k0) = o;
        }
    }
}

extern "C" void kernel_launch(void* const* d_in, const int* in_sizes, int n_in,
                              void* d_out, int out_size, void* d_ws, size_t ws_size,
                              hipStream_t stream) {
    const float* Q    = (const float*)d_in[0];
    const float* K    = (const float*)d_in[1];
    const float* V    = (const float*)d_in[2];
    const int*   mask = (const int*)d_in[3];

    float* ctx  = (float*)d_out;                           // (B,H,S,D)
    float* attn = (float*)d_out + (size_t)128 * Sn * Dn;   // (B,H,S,S)

    const size_t NELEM = (size_t)128 * Sn * Dn;            // 8,388,608
    const size_t MWORDS = (size_t)128 * Sn * 16;           // 2,097,152 u64
    const size_t NEED  = NELEM * 2 * 3 + MWORDS * 8;       // 50.3MB + 16.8MB

    if (ws_size >= NEED) {
        unsigned short* Khi = (unsigned short*)d_ws;
        unsigned short* Klo = Khi + NELEM;
        unsigned short* VT  = Klo + NELEM;
        unsigned long long* MWp = (unsigned long long*)((char*)d_ws + NELEM * 2 * 3);
        prep_k<<<4096, 256, 0, stream>>>(K, Khi, Klo);
        prep_v<<<2048, 256, 0, stream>>>(V, VT);
        prep_m<<<2048, 256, 0, stream>>>(mask, MWp);
        fused_attn_b<<<128 * 64, 256, 0, stream>>>(Khi, Klo, VT, Q, MWp, attn, ctx);
    } else {
        fused_attn_fb<<<128 * 64, 256, 0, stream>>>(Q, K, V, mask, attn, ctx);
    }
}